// Round 10
// baseline (2198.967 us; speedup 1.0000x reference)
//
#include <hip/hip_runtime.h>
#include <hip/hip_bf16.h>
#include <stdint.h>

// Problem constants
#define TT 256
#define BH 65536        // B*H
#define B4H 262144      // B*4H
#define OUT_HL 16777216
#define OUT_CL (16777216 + 131072)
#define NBLK 256
#define SLAB 65536      // ushorts per [64][1024] bf16 activation slab
#define XGSZ 262144     // floats per xg slab [4096 col][64 b]

typedef __attribute__((ext_vector_type(8))) short bf16x8;
typedef __attribute__((ext_vector_type(4))) float f32x4;
typedef __attribute__((ext_vector_type(4))) unsigned int u32x4;

__device__ __forceinline__ ushort f2bf(float v) {
    union { float f; uint32_t u; } x; x.f = v;
    uint32_t r = x.u + 0x7fff + ((x.u >> 16) & 1);
    return (ushort)(r >> 16);
}
__device__ __forceinline__ float sigf(float x) { return 1.f / (1.f + __expf(-x)); }

// Fragment-major layout for [64][1024] bf16 activation slabs:
//   off(b,k) = (b>>4)*16384 + (k>>5)*512 + ((k>>3)&3)*128 + (b&15)*8 + (k&7)

// Build Wt[l][col'][k] bf16, col' = u*4+g for source column col=g*1024+u.
// sc stores: region is later reused as xg rings (first write gated by fS).
__global__ __launch_bounds__(256) void k_prep_wt(const float* __restrict__ wih,
                                                 const float* __restrict__ whh,
                                                 ushort* __restrict__ Wt) {
    __shared__ ushort tile[64][65];
    const int l = blockIdx.z;
    const int k0 = blockIdx.x * 64;
    const int col0 = blockIdx.y * 64;
    const int tid = threadIdx.x;
    const int cl = tid & 63, ks = tid >> 6;
    const float* src;
    int krow0;
    if (k0 < 1024) { src = wih + (size_t)l * 1024 * 4096; krow0 = k0; }
    else           { src = whh + (size_t)l * 1024 * 4096; krow0 = k0 - 1024; }
#pragma unroll
    for (int i = 0; i < 16; ++i) {
        int kl = ks + i * 4;
        tile[kl][cl] = f2bf(src[(size_t)(krow0 + kl) * 4096 + col0 + cl]);
    }
    __syncthreads();
    const int g0 = col0 >> 10, ub = col0 & 1023;
    ushort* dst = Wt + (size_t)l * 4096 * 2048;
    const int klane = tid & 63;
#pragma unroll
    for (int i = 0; i < 16; ++i) {
        int cl2 = (tid >> 6) + i * 4;
        int row = (ub + cl2) * 4 + g0;
        ushort* p = dst + (size_t)row * 2048 + k0 + klane;
        uint v = (uint)tile[klane][cl2];
        asm volatile("global_store_short %0, %1, off sc0 sc1"
                     :: "v"(p), "v"(v) : "memory");
    }
}

// x -> bf16 fragment-major xbfF[t][...] (plain stores; kernel boundary flushes)
__global__ __launch_bounds__(256) void k_cast_x(const float* __restrict__ x,
                                                ushort* __restrict__ xbfF) {
    int i = blockIdx.x * 256 + threadIdx.x;   // [256 t][64 b][128 k8]
    int k8 = i & 127, b = (i >> 7) & 63, t = i >> 13;
    const float4* xs = (const float4*)(x + (((size_t)t * 64 + b) * 1024 + k8 * 8));
    float4 a = xs[0], c = xs[1];
    uint4 pk;
    pk.x = (uint)f2bf(a.x) | ((uint)f2bf(a.y) << 16);
    pk.y = (uint)f2bf(a.z) | ((uint)f2bf(a.w) << 16);
    pk.z = (uint)f2bf(c.x) | ((uint)f2bf(c.y) << 16);
    pk.w = (uint)f2bf(c.z) | ((uint)f2bf(c.w) << 16);
    size_t off = (size_t)t * SLAB + (size_t)(b >> 4) * 16384 +
                 (size_t)(k8 >> 2) * 512 + (size_t)(k8 & 3) * 128 + (size_t)(b & 15) * 8;
    *(uint4*)(xbfF + off) = pk;
}

// const[l][b][col] = a0[b,:] @ W_ah[l][:,col] + bias_ah + bias_ih + bias_hh
__global__ __launch_bounds__(256) void k_const(const float* __restrict__ attn,
                                               const float* __restrict__ wah,
                                               const float* __restrict__ bah,
                                               const float* __restrict__ bih,
                                               const float* __restrict__ bhh,
                                               float* __restrict__ constg) {
    const int tid = threadIdx.x;
    const int col = blockIdx.x * 256 + tid;
    const int b0 = blockIdx.y * 8;
    const int l = blockIdx.z;
    const float* W = wah + (size_t)l * 512 * 4096;
    float acc[8] = {0.f, 0.f, 0.f, 0.f, 0.f, 0.f, 0.f, 0.f};
    for (int k = 0; k < 512; ++k) {
        float wv = W[(size_t)k * 4096 + col];
#pragma unroll
        for (int j = 0; j < 8; ++j) acc[j] += attn[(b0 + j) * 512 + k] * wv;
    }
    float bias = bah[l * 4096 + col] + bih[l * 4096 + col] + bhh[l * 4096 + col];
    float* cg = constg + (size_t)l * B4H;
#pragma unroll
    for (int j = 0; j < 8; ++j) cg[(size_t)(b0 + j) * 4096 + col] = acc[j] + bias;
}

// h0 -> fragment-major initial slabs; zero flags
__global__ __launch_bounds__(256) void k_init(const float* __restrict__ h0,
                                              ushort* __restrict__ hs0F,
                                              ushort* __restrict__ h1s0,
                                              unsigned* __restrict__ flags) {
    int i = blockIdx.x * 256 + threadIdx.x;   // [2 l][64 b][128 k8] = 16384
    if (i < 16384) {
        int k8 = i & 127, b = (i >> 7) & 63, l = i >> 13;
        const float* src = h0 + ((size_t)(l * 64 + b) * 1024 + k8 * 8);
        uint4 pk;
        pk.x = (uint)f2bf(src[0]) | ((uint)f2bf(src[1]) << 16);
        pk.y = (uint)f2bf(src[2]) | ((uint)f2bf(src[3]) << 16);
        pk.z = (uint)f2bf(src[4]) | ((uint)f2bf(src[5]) << 16);
        pk.w = (uint)f2bf(src[6]) | ((uint)f2bf(src[7]) << 16);
        size_t off = (size_t)(b >> 4) * 16384 + (size_t)(k8 >> 2) * 512 +
                     (size_t)(k8 & 3) * 128 + (size_t)(b & 15) * 8;
        *(uint4*)((l == 0 ? hs0F : h1s0) + off) = pk;
    }
    if (i < 512) flags[i] = 0u;   // fS[256], fAp[64], fA[64], fB[64], fC[64]
}

// ---- inline-asm helpers ----
#define ISSUE8(BUF, BASE)                                                      \
    do { _Pragma("unroll")                                                     \
        for (int _i = 0; _i < 8; ++_i)                                         \
            asm volatile("global_load_dwordx4 %0, %1, off"                     \
                         : "=v"(BUF[_i]) : "v"((BASE) + _i * 512)); } while (0)
#define ISSUE8_SC(BUF, BASE)                                                   \
    do { _Pragma("unroll")                                                     \
        for (int _i = 0; _i < 8; ++_i)                                         \
            asm volatile("global_load_dwordx4 %0, %1, off sc0 sc1"             \
                         : "=v"(BUF[_i]) : "v"((BASE) + _i * 512)); } while (0)

#define MFMA(A, B, C) __builtin_amdgcn_mfma_f32_16x16x32_bf16(A, B, C, 0, 0, 0)

// Wait (N outstanding allowed), then 8 ktg x 4 nt = 32 MFMAs.
#define CHUNK8(BUF, KTG0, N)                                                   \
    do {                                                                       \
        asm volatile("s_waitcnt vmcnt(" #N ")" ::: "memory");                  \
        __builtin_amdgcn_sched_barrier(0x100);                                 \
        _Pragma("unroll")                                                      \
        for (int _i = 0; _i < 8; ++_i) {                                       \
            const ushort* _wb = wlds + ((size_t)((KTG0) + _i) * 256 + lane) * 8; \
            bf16x8 _b0 = *(const bf16x8*)(_wb);                                \
            bf16x8 _b1 = *(const bf16x8*)(_wb + 512);                          \
            bf16x8 _b2 = *(const bf16x8*)(_wb + 1024);                         \
            bf16x8 _b3 = *(const bf16x8*)(_wb + 1536);                         \
            acc0 = MFMA(BUF[_i], _b0, acc0);                                   \
            acc1 = MFMA(BUF[_i], _b1, acc1);                                   \
            acc2 = MFMA(BUF[_i], _b2, acc2);                                   \
            acc3 = MFMA(BUF[_i], _b3, acc3);                                   \
        }                                                                      \
    } while (0)

// 64-flag poll, one wave, 1 flag/lane.
#define POLLALL64(FB, TGT)                                                     \
    do { const unsigned* _fp = (FB) + lane;                                    \
        while (true) { unsigned _f;                                            \
            asm volatile("global_load_dword %0, %1, off sc0 sc1\n\t"           \
                         "s_waitcnt vmcnt(0)" : "=v"(_f) : "v"(_fp) : "memory"); \
            if (__all(_f >= (unsigned)(TGT))) break;                           \
            __builtin_amdgcn_s_sleep(1); } } while (0)

// single-flag poll, lane-uniform
#define POLLONE(FP, TGT)                                                       \
    do { while (true) { unsigned _f;                                           \
            asm volatile("global_load_dword %0, %1, off sc0 sc1\n\t"           \
                         "s_waitcnt vmcnt(0)" : "=v"(_f) : "v"(FP) : "memory"); \
            if (_f >= (unsigned)(TGT)) break;                                  \
            __builtin_amdgcn_s_sleep(1); } } while (0)

// all 256 staging flags == 1 (4/lane)
#define POLLS256(FB)                                                           \
    do { const unsigned* _fp = (FB) + lane * 4;                                \
        while (true) { u32x4 _f;                                               \
            asm volatile("global_load_dwordx4 %0, %1, off sc0 sc1\n\t"         \
                         "s_waitcnt vmcnt(0)" : "=v"(_f) : "v"(_fp) : "memory"); \
            if (__all(_f.x && _f.y && _f.z && _f.w)) break;                    \
            __builtin_amdgcn_s_sleep(1); } } while (0)

// 4-stage pipelined 2-layer LSTM. 64 blocks per role, 16 units per block.
// role0 A': xg0[t] = x[t]@W_ih0 + const0          (static in; throttled)
// role1 A : h0[t+1] = cell(xg0[t] + hs0F[t]@W_hh0) -> hs0F[t+1], fA
// role2 B : xg1[t] = hs0F[t+1]@W_ih1 + const1      (waits all fA >= t+1)
// role3 C : h1[t] = cell(xg1[t] + h1[t-1]@W_hh1)   -> xbfF[t] (slab reuse), out
// Aliases: xg0 ring(16) + xg1 ring(8) over Wt (gated by fS staging flags);
// h1 ring over consumed xbfF slabs (C at t runs after A' read x[t], by chain).
__global__ __launch_bounds__(512, 2) void k_persist(
        ushort* xbfF,                    // x slabs; also h1 ring (slot t)
        ushort* hs0F,
        const ushort* __restrict__ h1s0,
        const ushort* __restrict__ Wt,
        const float* __restrict__ constg,
        const float* __restrict__ c0,
        float* __restrict__ out,
        unsigned* flags,
        float* xg0, float* xg1) {
    __shared__ ushort wlds[65536];       // [32 ktg][4 nt][64 lane][8] = 128 KiB
    __shared__ float gt[4][16][68];      // [m][row=b&15][64 col + pad]

    const int tid = threadIdx.x;
    const int w = tid >> 6, lane = tid & 63;
    const int kh = w >> 2, m = w & 3;
    const int bid = blockIdx.x;
    const int role = bid >> 6, j = bid & 63;
    const int lsel = role >> 1;              // 0,0,1,1
    const int hbase = (role & 1) * 1024;     // ih / hh half of K
    unsigned* fS  = flags;
    unsigned* fAp = flags + 256;
    unsigned* fA  = flags + 320;
    unsigned* fB  = flags + 384;
    unsigned* fC  = flags + 448;

    // ---- stage this role's 64 cols x 1024 k matrix into LDS (sc loads) ----
    {
        bf16x8 vst[16];
#pragma unroll
        for (int i = 0; i < 16; ++i) {
            int c = i * 512 + tid;           // [0,8192) chunks of 16B
            int ktg = c >> 8, nt = (c >> 6) & 3, lp = c & 63;
            int colp = 64 * j + nt * 16 + (lp & 15);
            int kk = hbase + ktg * 32 + (lp >> 4) * 8;
            const ushort* src = Wt + ((size_t)(lsel * 4096 + colp)) * 2048 + kk;
            asm volatile("global_load_dwordx4 %0, %1, off sc0 sc1"
                         : "=v"(vst[i]) : "v"(src));
        }
        asm volatile("s_waitcnt vmcnt(0)" ::: "memory");
        __builtin_amdgcn_sched_barrier(0);
#pragma unroll
        for (int i = 0; i < 16; ++i) {
            int c = i * 512 + tid;
            *(bf16x8*)(wlds + (size_t)c * 8) = vst[i];
        }
    }
    __syncthreads();
    if (tid == 0) {                          // signal "staged"
        unsigned one = 1u; unsigned* fp = fS + bid;
        asm volatile("global_store_dword %0, %1, off sc0 sc1"
                     :: "v"(fp), "v"(one) : "memory");
    }

    // ---- launch-invariant per-thread state ----
    const int cc = lane & 15, r0 = (lane >> 4) * 4;
    // const regs for projector roles (0,2): cst[nt][r]
    f32x4 cst0 = {0,0,0,0}, cst1 = {0,0,0,0}, cst2 = {0,0,0,0}, cst3 = {0,0,0,0};
    if (role == 0 || role == 2) {
#pragma unroll
        for (int nt = 0; nt < 4; ++nt) {
            int colp = nt * 16 + cc;
            size_t base = (size_t)lsel * B4H + (size_t)(cc & 3) * 1024 + 16 * j + (colp >> 2);
            f32x4 v;
#pragma unroll
            for (int r = 0; r < 4; ++r)
                v[r] = constg[base + (size_t)(m * 16 + r0 + r) * 4096];
            if (nt == 0) cst0 = v; else if (nt == 1) cst1 = v;
            else if (nt == 2) cst2 = v; else cst3 = v;
        }
    }
    // cell-state threads for recurrence roles (1,3): b = tid>>3, u = 16j + 2p{,+1}
    const int b_e = tid >> 3, p_e = tid & 7, up = p_e * 2;
    const int ug0 = 16 * j + up;
    float cregA = 0.f, cregB = 0.f;
    size_t hoffT = 0;
    if (role == 1 || role == 3) {
        cregA = c0[lsel * BH + b_e * 1024 + ug0];
        cregB = c0[lsel * BH + b_e * 1024 + ug0 + 1];
        hoffT = (size_t)(b_e >> 4) * 16384 + (size_t)(ug0 >> 5) * 512 +
                (size_t)((ug0 >> 3) & 3) * 128 + (size_t)(b_e & 15) * 8 + (ug0 & 7);
    }
    const size_t fro = (size_t)m * 16384 + (size_t)(kh * 16) * 512 + (size_t)lane * 8;
    __syncthreads();

    for (int t = 0; t < TT; ++t) {
        f32x4 acc0 = {0,0,0,0}, acc1 = {0,0,0,0}, acc2 = {0,0,0,0}, acc3 = {0,0,0,0};
        bf16x8 bufA[8], bufB[8];
        float xgv[8];

        // ---- input polls (recurrence-gated roles) ----
        if (role == 1) {
            if (w == 0) POLLALL64(fA, t);
            if (w == 1) POLLONE(fAp + j, t + 1);
            __syncthreads();
        } else if (role == 2) {
            if (w == 0) POLLALL64(fA, t + 1);
            if (w == 1 && t >= 7) POLLONE(fC + j, t - 6);
            __syncthreads();
        } else if (role == 3) {
            if (w == 0) POLLALL64(fC, t);
            if (w == 1) POLLONE(fB + j, t + 1);
            __syncthreads();
        }

        // ---- xg prefetch (roles 1,3): 8 scalars, issued before slab ----
        if (role == 1 || role == 3) {
            const float* xg = (role == 1) ? xg0 + (size_t)(t & 15) * XGSZ
                                          : xg1 + (size_t)(t & 7) * XGSZ;
#pragma unroll
            for (int e = 0; e < 2; ++e)
#pragma unroll
                for (int g = 0; g < 4; ++g) {
                    const float* p = xg + (size_t)((64 * j + (up + e) * 4 + g)) * 64 + b_e;
                    asm volatile("global_load_dword %0, %1, off sc0 sc1"
                                 : "=v"(xgv[e * 4 + g]) : "v"(p));
                }
        }

        // ---- slab ingest + MFMA (all roles) ----
        {
            const ushort* slab;
            if (role == 0)      slab = xbfF + (size_t)t * SLAB;           // sc
            else if (role == 1) slab = hs0F + (size_t)t * SLAB;
            else if (role == 2) slab = hs0F + (size_t)(t + 1) * SLAB;
            else                slab = (t == 0) ? h1s0 : xbfF + (size_t)(t - 1) * SLAB;
            const ushort* base = slab + fro;
            if (role == 0) { ISSUE8_SC(bufA, base); ISSUE8_SC(bufB, base + 4096); }
            else           { ISSUE8(bufA, base);    ISSUE8(bufB, base + 4096); }
            CHUNK8(bufA, kh * 16, 8);
            CHUNK8(bufB, kh * 16 + 8, 0);
        }

        // ---- kh merge ----
        if (kh == 1) {
#pragma unroll
            for (int r = 0; r < 4; ++r) {
                gt[m][r0 + r][0 * 16 + cc] = acc0[r];
                gt[m][r0 + r][1 * 16 + cc] = acc1[r];
                gt[m][r0 + r][2 * 16 + cc] = acc2[r];
                gt[m][r0 + r][3 * 16 + cc] = acc3[r];
            }
        }
        if (role == 0) {   // A' store gates: throttle + one-time fS
            if (w == 0 && t == 0) POLLS256(fS);
            if (w == 0 && t >= 15) POLLONE(fA + j, t - 14);
        }
        __syncthreads();

        if (role == 0 || role == 2) {
            // ---- projector: kh0 sums + const, stores xg col-major f32x4 ----
            if (kh == 0) {
                float* dst = (role == 0 ? xg0 + (size_t)(t & 15) * XGSZ
                                        : xg1 + (size_t)(t & 7) * XGSZ);
#pragma unroll
                for (int nt = 0; nt < 4; ++nt) {
                    f32x4 a = (nt == 0) ? acc0 : (nt == 1) ? acc1 : (nt == 2) ? acc2 : acc3;
                    f32x4 cs = (nt == 0) ? cst0 : (nt == 1) ? cst1 : (nt == 2) ? cst2 : cst3;
                    f32x4 v;
#pragma unroll
                    for (int r = 0; r < 4; ++r)
                        v[r] = a[r] + gt[m][r0 + r][nt * 16 + cc] + cs[r];
                    float* ap = dst + (size_t)(64 * j + nt * 16 + cc) * 64 + m * 16 + r0;
                    asm volatile("global_store_dwordx4 %0, %1, off sc0 sc1"
                                 :: "v"(ap), "v"(v) : "memory");
                }
            }
            asm volatile("s_waitcnt vmcnt(0)" ::: "memory");
            __syncthreads();
            if (tid == 0) {
                unsigned tgt = (unsigned)(t + 1);
                unsigned* fp = (role == 0 ? fAp : fB) + j;
                asm volatile("global_store_dword %0, %1, off sc0 sc1"
                             :: "v"(fp), "v"(tgt) : "memory");
            }
        } else {
            // ---- recurrence: kh0 folds into gt, then balanced cell epilogue ----
            if (kh == 0) {
#pragma unroll
                for (int r = 0; r < 4; ++r) {
                    gt[m][r0 + r][0 * 16 + cc] += acc0[r];
                    gt[m][r0 + r][1 * 16 + cc] += acc1[r];
                    gt[m][r0 + r][2 * 16 + cc] += acc2[r];
                    gt[m][r0 + r][3 * 16 + cc] += acc3[r];
                }
            }
            __syncthreads();
            f32x4 va = *(const f32x4*)&gt[b_e >> 4][b_e & 15][up * 4];
            f32x4 vb = *(const f32x4*)&gt[b_e >> 4][b_e & 15][up * 4 + 4];
            float giA = va[0] + xgv[0], gfA = va[1] + xgv[1];
            float ggA = va[2] + xgv[2], goA = va[3] + xgv[3];
            float giB = vb[0] + xgv[4], gfB = vb[1] + xgv[5];
            float ggB = vb[2] + xgv[6], goB = vb[3] + xgv[7];
            float cnA = sigf(gfA) * cregA + sigf(giA) * (2.f * sigf(2.f * ggA) - 1.f);
            float hvA = sigf(goA) * (2.f * sigf(2.f * cnA) - 1.f);
            float cnB = sigf(gfB) * cregB + sigf(giB) * (2.f * sigf(2.f * ggB) - 1.f);
            float hvB = sigf(goB) * (2.f * sigf(2.f * cnB) - 1.f);
            cregA = cnA; cregB = cnB;
            uint hb = (uint)f2bf(hvA) | ((uint)f2bf(hvB) << 16);
            ushort* hdst = (role == 1 ? hs0F + (size_t)(t + 1) * SLAB
                                      : xbfF + (size_t)t * SLAB) + hoffT;
            asm volatile("global_store_dword %0, %1, off sc0 sc1"
                         :: "v"(hdst), "v"(hb) : "memory");
            asm volatile("s_waitcnt vmcnt(0)" ::: "memory");
            __syncthreads();
            if (tid == 0) {
                unsigned tgt = (unsigned)(t + 1);
                unsigned* fp = (role == 1 ? fA : fC) + j;
                asm volatile("global_store_dword %0, %1, off sc0 sc1"
                             :: "v"(fp), "v"(tgt) : "memory");
            }
            // exit-only stores after signal (overlap next poll)
            if (role == 3) {
                float2 ov; ov.x = hvA; ov.y = hvB;
                *(float2*)(out + (size_t)t * BH + (size_t)b_e * 1024 + ug0) = ov;
                if (t == TT - 1) {
                    int idx = b_e * 1024 + ug0;
                    out[OUT_HL + BH + idx] = hvA; out[OUT_HL + BH + idx + 1] = hvB;
                    out[OUT_CL + BH + idx] = cnA; out[OUT_CL + BH + idx + 1] = cnB;
                }
            } else if (t == TT - 1) {
                int idx = b_e * 1024 + ug0;
                out[OUT_HL + idx] = hvA; out[OUT_HL + idx + 1] = hvB;
                out[OUT_CL + idx] = cnA; out[OUT_CL + idx + 1] = cnB;
            }
        }
    }
}

extern "C" void kernel_launch(void* const* d_in, const int* in_sizes, int n_in,
                              void* d_out, int out_size, void* d_ws, size_t ws_size,
                              hipStream_t stream) {
    const float* attn = (const float*)d_in[0];
    const float* x    = (const float*)d_in[1];
    const float* h0   = (const float*)d_in[3];
    const float* c0   = (const float*)d_in[4];
    const float* wah  = (const float*)d_in[5];
    const float* wih  = (const float*)d_in[6];
    const float* whh  = (const float*)d_in[7];
    const float* bah  = (const float*)d_in[8];
    const float* bih  = (const float*)d_in[9];
    const float* bhh  = (const float*)d_in[10];
    float* out = (float*)d_out;

    char* ws = (char*)d_ws;
    ushort*   Wt     = (ushort*)(ws);               // [2][4096][2048] bf16 : 33,554,432
    float*    xg0    = (float*)(ws);                //   alias: 16 x 1MB ring
    float*    xg1    = (float*)(ws + 16777216);     //   alias: 8 x 1MB ring
    ushort*   xbfF   = (ushort*)(ws + 33554432);    // 256 x slabs; also h1 ring
    ushort*   hs0F   = (ushort*)(ws + 67108864);    // 257 slabs : 33,685,504
    ushort*   h1s0   = (ushort*)(ws + 100794368);   // h1 init slab : 131,072
    float*    constg = (float*)(ws + 100925440);    // [2][64][4096] : 2,097,152
    unsigned* flags  = (unsigned*)(ws + 103022592); // fS256,fAp64,fA64,fB64,fC64
    // total 103,024,640 B (within round-4's proven footprint)

    hipLaunchKernelGGL(k_prep_wt, dim3(32, 64, 2), dim3(256), 0, stream, wih, whh, Wt);
    hipLaunchKernelGGL(k_cast_x, dim3(8192), dim3(256), 0, stream, x, xbfF);
    hipLaunchKernelGGL(k_const, dim3(16, 8, 2), dim3(256), 0, stream, attn, wah, bah, bih, bhh, constg);
    hipLaunchKernelGGL(k_init, dim3(64), dim3(256), 0, stream, h0, hs0F, h1s0, flags);

    void* args[] = { (void*)&xbfF, (void*)&hs0F, (void*)&h1s0, (void*)&Wt,
                     (void*)&constg, (void*)&c0, (void*)&out, (void*)&flags,
                     (void*)&xg0, (void*)&xg1 };
    hipLaunchCooperativeKernel((void*)k_persist, dim3(NBLK), dim3(512), args, 0, stream);
}

// Round 11
// 2063.741 us; speedup vs baseline: 1.0655x; 1.0655x over previous
//
#include <hip/hip_runtime.h>
#include <hip/hip_bf16.h>
#include <stdint.h>

// Problem constants
#define TT 256
#define BH 65536        // B*H
#define B4H 262144      // B*4H
#define OUT_HL 16777216
#define OUT_CL (16777216 + 131072)
#define NBLK 256
#define SLAB 65536      // ushorts per [64][1024] bf16 activation slab

typedef __attribute__((ext_vector_type(8))) short bf16x8;
typedef __attribute__((ext_vector_type(4))) float f32x4;
typedef __attribute__((ext_vector_type(4))) unsigned int u32x4;
typedef __attribute__((ext_vector_type(2))) unsigned int u32x2;

__device__ __forceinline__ ushort f2bf(float v) {
    union { float f; uint32_t u; } x; x.f = v;
    uint32_t r = x.u + 0x7fff + ((x.u >> 16) & 1);
    return (ushort)(r >> 16);
}
__device__ __forceinline__ float sigf(float x) { return 1.f / (1.f + __expf(-x)); }

// Fragment-major layout for [64][1024] bf16 activation slabs:
//   off(b,k) = (b>>4)*16384 + (k>>5)*512 + ((k>>3)&3)*128 + (b&15)*8 + (k&7)

// Build Wt[l][col'][k] bf16, col' = u*4+g for source column col=g*1024+u.
// sc stores: region is later reused as the layer-1 h ring (plain cached reads).
__global__ __launch_bounds__(256) void k_prep_wt(const float* __restrict__ wih,
                                                 const float* __restrict__ whh,
                                                 ushort* __restrict__ Wt) {
    __shared__ ushort tile[64][65];
    const int l = blockIdx.z;
    const int k0 = blockIdx.x * 64;
    const int col0 = blockIdx.y * 64;
    const int tid = threadIdx.x;
    const int cl = tid & 63, ks = tid >> 6;
    const float* src;
    int krow0;
    if (k0 < 1024) { src = wih + (size_t)l * 1024 * 4096; krow0 = k0; }
    else           { src = whh + (size_t)l * 1024 * 4096; krow0 = k0 - 1024; }
#pragma unroll
    for (int i = 0; i < 16; ++i) {
        int kl = ks + i * 4;
        tile[kl][cl] = f2bf(src[(size_t)(krow0 + kl) * 4096 + col0 + cl]);
    }
    __syncthreads();
    const int g0 = col0 >> 10, ub = col0 & 1023;
    ushort* dst = Wt + (size_t)l * 4096 * 2048;
    const int klane = tid & 63;
#pragma unroll
    for (int i = 0; i < 16; ++i) {
        int cl2 = (tid >> 6) + i * 4;
        int row = (ub + cl2) * 4 + g0;
        ushort* p = dst + (size_t)row * 2048 + k0 + klane;
        uint v = (uint)tile[klane][cl2];
        asm volatile("global_store_short %0, %1, off sc0 sc1"
                     :: "v"(p), "v"(v) : "memory");
    }
}

// x -> bf16 fragment-major xbfF[t][...]
__global__ __launch_bounds__(256) void k_cast_x(const float* __restrict__ x,
                                                ushort* __restrict__ xbfF) {
    int i = blockIdx.x * 256 + threadIdx.x;   // [256 t][64 b][128 k8]
    int k8 = i & 127, b = (i >> 7) & 63, t = i >> 13;
    const float4* xs = (const float4*)(x + (((size_t)t * 64 + b) * 1024 + k8 * 8));
    float4 a = xs[0], c = xs[1];
    uint4 pk;
    pk.x = (uint)f2bf(a.x) | ((uint)f2bf(a.y) << 16);
    pk.y = (uint)f2bf(a.z) | ((uint)f2bf(a.w) << 16);
    pk.z = (uint)f2bf(c.x) | ((uint)f2bf(c.y) << 16);
    pk.w = (uint)f2bf(c.z) | ((uint)f2bf(c.w) << 16);
    size_t off = (size_t)t * SLAB + (size_t)(b >> 4) * 16384 +
                 (size_t)(k8 >> 2) * 512 + (size_t)(k8 & 3) * 128 + (size_t)(b & 15) * 8;
    *(uint4*)(xbfF + off) = pk;
}

// const[l][b][col] = a0[b,:] @ W_ah[l][:,col] + bias_ah + bias_ih + bias_hh
__global__ __launch_bounds__(256) void k_const(const float* __restrict__ attn,
                                               const float* __restrict__ wah,
                                               const float* __restrict__ bah,
                                               const float* __restrict__ bih,
                                               const float* __restrict__ bhh,
                                               float* __restrict__ constg) {
    const int tid = threadIdx.x;
    const int col = blockIdx.x * 256 + tid;
    const int b0 = blockIdx.y * 8;
    const int l = blockIdx.z;
    const float* W = wah + (size_t)l * 512 * 4096;
    float acc[8] = {0.f, 0.f, 0.f, 0.f, 0.f, 0.f, 0.f, 0.f};
    for (int k = 0; k < 512; ++k) {
        float wv = W[(size_t)k * 4096 + col];
#pragma unroll
        for (int j = 0; j < 8; ++j) acc[j] += attn[(b0 + j) * 512 + k] * wv;
    }
    float bias = bah[l * 4096 + col] + bih[l * 4096 + col] + bhh[l * 4096 + col];
    float* cg = constg + (size_t)l * B4H;
#pragma unroll
    for (int j = 0; j < 8; ++j) cg[(size_t)(b0 + j) * 4096 + col] = acc[j] + bias;
}

// h0 -> fragment-major initial slabs; zero flags
__global__ __launch_bounds__(256) void k_init(const float* __restrict__ h0,
                                              ushort* __restrict__ hs0F,
                                              ushort* __restrict__ h1s0,
                                              unsigned* __restrict__ flags) {
    int i = blockIdx.x * 256 + threadIdx.x;   // [2 l][64 b][128 k8] = 16384
    if (i < 16384) {
        int k8 = i & 127, b = (i >> 7) & 63, l = i >> 13;
        const float* src = h0 + ((size_t)(l * 64 + b) * 1024 + k8 * 8);
        uint4 pk;
        pk.x = (uint)f2bf(src[0]) | ((uint)f2bf(src[1]) << 16);
        pk.y = (uint)f2bf(src[2]) | ((uint)f2bf(src[3]) << 16);
        pk.z = (uint)f2bf(src[4]) | ((uint)f2bf(src[5]) << 16);
        pk.w = (uint)f2bf(src[6]) | ((uint)f2bf(src[7]) << 16);
        size_t off = (size_t)(b >> 4) * 16384 + (size_t)(k8 >> 2) * 512 +
                     (size_t)(k8 & 3) * 128 + (size_t)(b & 15) * 8;
        *(uint4*)((l == 0 ? hs0F : h1s0) + off) = pk;
    }
    if (i < NBLK) flags[i] = 0u;
}

// ---- inline-asm helpers ----
#define ISSUE(BUF, BASE)                                                       \
    do { _Pragma("unroll")                                                     \
        for (int _i = 0; _i < 8; ++_i)                                         \
            asm volatile("global_load_dwordx4 %0, %1, off"                     \
                         : "=v"(BUF[_i]) : "v"((BASE) + _i * 512)); } while (0)

// Wait (N outstanding allowed), then 8 ktg x 2 nt = 16 MFMAs.
#define CHUNK(BUF, KTG0, N, A0, A1)                                            \
    do {                                                                       \
        asm volatile("s_waitcnt vmcnt(" #N ")" ::: "memory");                  \
        __builtin_amdgcn_sched_barrier(0x100);                                 \
        _Pragma("unroll")                                                      \
        for (int _i = 0; _i < 8; ++_i) {                                       \
            int _ktg = (KTG0) + _i;                                            \
            bf16x8 _b0 = *(const bf16x8*)(wlds + (size_t)_ktg * 1024 + lane * 8);       \
            bf16x8 _b1 = *(const bf16x8*)(wlds + (size_t)_ktg * 1024 + 512 + lane * 8); \
            A0 = __builtin_amdgcn_mfma_f32_16x16x32_bf16(BUF[_i], _b0, A0, 0, 0, 0);    \
            A1 = __builtin_amdgcn_mfma_f32_16x16x32_bf16(BUF[_i], _b1, A1, 0, 0, 0);    \
        }                                                                      \
    } while (0)

// 128-flag poll, single wave, 2 flags/lane.
#define POLL128(FB, TGT)                                                       \
    do {                                                                       \
        const unsigned* _fp = (FB) + lane * 2;                                 \
        while (true) {                                                         \
            u32x2 _f;                                                          \
            asm volatile("global_load_dwordx2 %0, %1, off sc0 sc1\n\t"         \
                         "s_waitcnt vmcnt(0)"                                  \
                         : "=v"(_f) : "v"(_fp) : "memory");                    \
            if (__all(_f.x >= (TGT) && _f.y >= (TGT))) break;                  \
            __builtin_amdgcn_s_sleep(1);                                       \
        }                                                                      \
    } while (0)

// Persistent 2-layer LSTM, layer-split with cross-iteration load pipelining.
// Blocks 0-127 = layer0 (8 units each), 128-255 = layer1.
// L0 iter s: x[s] MFMA (preloaded) -> reissue x[s+1] -> h[s] MFMA (preissued)
//   -> epilogue -> store hs0F[s+1] -> drain -> signal f0=s+1
//   -> poll f0>=s+1 (peer skew) -> preissue h[s+1].
// L1 iter s (t=s-1): poll f1>=s (peer skew) -> issue ring[t-1] -> MFMA both
//   (hs0F[s] preissued) -> epilogue -> store ring[t] -> drain -> signal f1=s+1
//   -> out rows -> poll f0>=s+1 (pre-satisfied: L0 free-runs ahead)
//   -> preissue hs0F[s+1].
// Ring aliasing over Wt: slot t first written at iter t+1, gated by f0>=1
// (all L0 staging done) / f1>=129 (all L1 staging done). Same proof as r9.
__global__ __launch_bounds__(512, 2) void k_persist(
        const ushort* __restrict__ xbfF,
        ushort* __restrict__ hs0F,
        const ushort* __restrict__ h1s0,
        ushort* Wt,                       // staging source + h1 ring (aliased)
        const float* __restrict__ constg,
        const float* __restrict__ c0,
        float* __restrict__ out,
        unsigned* __restrict__ flags) {
    __shared__ ushort wlds[65536];          // [64 ktg][2 nt][64 lane][8] = 128 KiB
    __shared__ float gt[2][4][2][16][18];   // [kh][m][nt][b&15][col'] 18 KiB

    const int tid = threadIdx.x;
    const int w = tid >> 6, lane = tid & 63;
    const int kh = w >> 2, m = w & 3;
    const int bid = blockIdx.x;
    const int layer = bid >> 7, ub = bid & 127;
    const int u0g = ub * 8;

    // ---- stage this layer's 32 gate-cols x 2048 k into LDS (sc loads) ----
    {
        bf16x8 vst[16];
#pragma unroll
        for (int i = 0; i < 16; ++i) {
            int c = i * 512 + tid;          // 0..8191 chunks of 16B
            int lp = c & 63, nt = (c >> 6) & 1, ktg = c >> 7;
            int colp = u0g * 4 + nt * 16 + (lp & 15);
            int kk = ktg * 32 + (lp >> 4) * 8;
            const ushort* src = Wt + ((size_t)(layer * 4096 + colp)) * 2048 + kk;
            asm volatile("global_load_dwordx4 %0, %1, off sc0 sc1"
                         : "=v"(vst[i]) : "v"(src));
        }
        asm volatile("s_waitcnt vmcnt(0)" ::: "memory");
        __builtin_amdgcn_sched_barrier(0);
#pragma unroll
        for (int i = 0; i < 16; ++i) {
            int c = i * 512 + tid;
            *(bf16x8*)(wlds + (size_t)c * 8) = vst[i];
        }
    }

    // ---- per-thread epilogue cell: b_e = w*8 + lane/8, u_e = u0g + lane%8 ----
    const int b_e = (w << 3) | (lane >> 3);
    const int u_off = lane & 7;
    const int u_e = u0g + u_off;
    float cg[4];
#pragma unroll
    for (int g = 0; g < 4; ++g)
        cg[g] = constg[(size_t)layer * B4H + (size_t)b_e * 4096 + g * 1024 + u_e];
    float creg = c0[layer * BH + b_e * 1024 + u_e];
    const int mb = b_e >> 4, blb = b_e & 15, ntb = u_off >> 2, cpb = (u_off & 3) * 4;
    const size_t hoffL = (size_t)mb * 16384 + (size_t)(ub >> 2) * 512 +
                         (size_t)(ub & 3) * 128 + (size_t)blb * 8;

    const size_t fro = (size_t)m * 16384 + (size_t)(kh * 16) * 512 + (size_t)lane * 8;
    unsigned* f0 = flags;
    unsigned* f1 = flags + 128;

    __syncthreads();

    // loop-carried in-flight buffers (16 loads each pair)
    bf16x8 bufXa[8], bufXb[8];   // L0: x[s+1] pre-issue; L1: ring (intra-iter)
    bf16x8 bufHa[8], bufHb[8];   // hs0F pre-issue (both layers)

    if (layer == 0) {
        // prologue: issue x[0] then h[0] (x older)
        { const ushort* ax = xbfF + fro; ISSUE(bufXa, ax); ISSUE(bufXb, ax + 4096); }
        { const ushort* ah = hs0F + fro; ISSUE(bufHa, ah); ISSUE(bufHb, ah + 4096); }
        for (int s = 0; s < TT; ++s) {
            f32x4 aE0 = {0,0,0,0}, aO0 = {0,0,0,0};
            f32x4 aE1 = {0,0,0,0}, aO1 = {0,0,0,0};
            // 1) x[s] MFMA (retires bufX; bufH stays outstanding)
            CHUNK(bufXa, kh * 16,     16, aE0, aE1);
            CHUNK(bufXb, kh * 16 + 8, 16, aO0, aO1);
            // 2) reissue x[s+1] (clamped; s=255 issues dummy x[0], never used)
            { const ushort* ax = xbfF + (size_t)((s + 1) & 255) * SLAB + fro;
              ISSUE(bufXa, ax); ISSUE(bufXb, ax + 4096); }
            // 3) h[s] MFMA (bufH oldest: 8 left + 16 x' -> 24; then 16)
            CHUNK(bufHa, 32 + kh * 16,     24, aE0, aE1);
            CHUNK(bufHb, 32 + kh * 16 + 8, 16, aO0, aO1);
            // 4) merge partials
            {
                const int cc = lane & 15, r0 = (lane >> 4) * 4;
#pragma unroll
                for (int r = 0; r < 4; ++r) {
                    gt[kh][m][0][r0 + r][cc] = aE0[r] + aO0[r];
                    gt[kh][m][1][r0 + r][cc] = aE1[r] + aO1[r];
                }
            }
            __syncthreads();
            // 5) balanced cell epilogue
            float g4[4];
#pragma unroll
            for (int g = 0; g < 4; ++g)
                g4[g] = gt[0][mb][ntb][blb][cpb + g] + gt[1][mb][ntb][blb][cpb + g] + cg[g];
            float si = sigf(g4[0]), sf = sigf(g4[1]), so = sigf(g4[3]);
            float cn = sf * creg + si * (2.f * sigf(2.f * g4[2]) - 1.f);
            float hv = so * (2.f * sigf(2.f * cn) - 1.f);
            creg = cn;
            uint hb = (uint)f2bf(hv);
            uint p0 = __shfl(hb, (lane & 56) + 0), p1 = __shfl(hb, (lane & 56) + 1);
            uint p2 = __shfl(hb, (lane & 56) + 2), p3 = __shfl(hb, (lane & 56) + 3);
            uint p4 = __shfl(hb, (lane & 56) + 4), p5 = __shfl(hb, (lane & 56) + 5);
            uint p6 = __shfl(hb, (lane & 56) + 6), p7 = __shfl(hb, (lane & 56) + 7);
            u32x4 hp;
            hp.x = (p0 & 0xffffu) | (p1 << 16);
            hp.y = (p2 & 0xffffu) | (p3 << 16);
            hp.z = (p4 & 0xffffu) | (p5 << 16);
            hp.w = (p6 & 0xffffu) | (p7 << 16);
            ushort* hdst = hs0F + (size_t)(s + 1) * SLAB + hoffL;
            if (u_off == 0)
                asm volatile("global_store_dwordx4 %0, %1, off sc0 sc1"
                             :: "v"(hdst), "v"(hp) : "memory");
            // 6) drain (h-store; also completes bufX')
            asm volatile("s_waitcnt vmcnt(0)" ::: "memory");
            __syncthreads();
            if (tid == 0) {
                unsigned tgt = (unsigned)(s + 1);
                unsigned* fp = f0 + ub;
                asm volatile("global_store_dword %0, %1, off sc0 sc1"
                             :: "v"(fp), "v"(tgt) : "memory");
            }
            // 7) exit-only stores
            if (s == TT - 1) {
                int idx = b_e * 1024 + u_e;
                out[OUT_HL + idx] = hv;
                out[OUT_CL + idx] = cn;
            }
            // 8) peer-skew poll + preissue h[s+1]
            if (s < TT - 1) {
                if (w == 0) POLL128(f0, (unsigned)(s + 1));
                __syncthreads();
                const ushort* ah = hs0F + (size_t)(s + 1) * SLAB + fro;
                ISSUE(bufHa, ah); ISSUE(bufHb, ah + 4096);
            }
        }
    } else {
        // prologue: wait layer0 step 0, issue hs0F[1]
        if (w == 0) POLL128(f0, 1u);
        __syncthreads();
        { const ushort* ah = hs0F + (size_t)1 * SLAB + fro;
          ISSUE(bufHa, ah); ISSUE(bufHb, ah + 4096); }
        for (int s = 1; s <= TT; ++s) {
            const int t1 = s - 1;
            f32x4 aE0 = {0,0,0,0}, aO0 = {0,0,0,0};
            f32x4 aE1 = {0,0,0,0}, aO1 = {0,0,0,0};
            // 1) peer-skew poll gates ring[t1-1]
            if (s >= 2) {
                if (w == 0) POLL128(f1, (unsigned)s);
                __syncthreads();
            }
            // 2) issue ring slab
            { const ushort* ar = (t1 == 0 ? h1s0
                                 : (const ushort*)Wt + (size_t)(t1 - 1) * SLAB) + fro;
              ISSUE(bufXa, ar); ISSUE(bufXb, ar + 4096); }
            // 3) MFMA: hs0F (preissued, oldest) then ring
            CHUNK(bufHa, kh * 16,          24, aE0, aE1);
            CHUNK(bufHb, kh * 16 + 8,      16, aO0, aO1);
            CHUNK(bufXa, 32 + kh * 16,      8, aE0, aE1);
            CHUNK(bufXb, 32 + kh * 16 + 8,  0, aO0, aO1);
            // 4) merge partials
            {
                const int cc = lane & 15, r0 = (lane >> 4) * 4;
#pragma unroll
                for (int r = 0; r < 4; ++r) {
                    gt[kh][m][0][r0 + r][cc] = aE0[r] + aO0[r];
                    gt[kh][m][1][r0 + r][cc] = aE1[r] + aO1[r];
                }
            }
            __syncthreads();
            // 5) balanced cell epilogue
            float g4[4];
#pragma unroll
            for (int g = 0; g < 4; ++g)
                g4[g] = gt[0][mb][ntb][blb][cpb + g] + gt[1][mb][ntb][blb][cpb + g] + cg[g];
            float si = sigf(g4[0]), sf = sigf(g4[1]), so = sigf(g4[3]);
            float cn = sf * creg + si * (2.f * sigf(2.f * g4[2]) - 1.f);
            float hv = so * (2.f * sigf(2.f * cn) - 1.f);
            creg = cn;
            uint hb = (uint)f2bf(hv);
            uint p0 = __shfl(hb, (lane & 56) + 0), p1 = __shfl(hb, (lane & 56) + 1);
            uint p2 = __shfl(hb, (lane & 56) + 2), p3 = __shfl(hb, (lane & 56) + 3);
            uint p4 = __shfl(hb, (lane & 56) + 4), p5 = __shfl(hb, (lane & 56) + 5);
            uint p6 = __shfl(hb, (lane & 56) + 6), p7 = __shfl(hb, (lane & 56) + 7);
            u32x4 hp;
            hp.x = (p0 & 0xffffu) | (p1 << 16);
            hp.y = (p2 & 0xffffu) | (p3 << 16);
            hp.z = (p4 & 0xffffu) | (p5 << 16);
            hp.w = (p6 & 0xffffu) | (p7 << 16);
            ushort* hdst = Wt + (size_t)t1 * SLAB + hoffL;   // ring slot t1
            if (u_off == 0)
                asm volatile("global_store_dwordx4 %0, %1, off sc0 sc1"
                             :: "v"(hdst), "v"(hp) : "memory");
            // 6) drain + signal
            asm volatile("s_waitcnt vmcnt(0)" ::: "memory");
            __syncthreads();
            if (tid == 0) {
                unsigned tgt = (unsigned)(s + 1);
                unsigned* fp = f1 + ub;
                asm volatile("global_store_dword %0, %1, off sc0 sc1"
                             :: "v"(fp), "v"(tgt) : "memory");
            }
            // 7) output rows (exit-only data; overlaps next iteration)
            {
                float o0 = __shfl(hv, (lane & 56) + 0), o1 = __shfl(hv, (lane & 56) + 1);
                float o2 = __shfl(hv, (lane & 56) + 2), o3 = __shfl(hv, (lane & 56) + 3);
                float o4 = __shfl(hv, (lane & 56) + 4), o5 = __shfl(hv, (lane & 56) + 5);
                float o6 = __shfl(hv, (lane & 56) + 6), o7 = __shfl(hv, (lane & 56) + 7);
                if (u_off == 0) {
                    float* op = out + (size_t)t1 * BH + (size_t)b_e * 1024 + u0g;
                    float4 v0 = {o0, o1, o2, o3}, v1 = {o4, o5, o6, o7};
                    *(float4*)op = v0;
                    *(float4*)(op + 4) = v1;
                }
                if (t1 == TT - 1) {
                    int idx = b_e * 1024 + u_e;
                    out[OUT_HL + BH + idx] = hv;
                    out[OUT_CL + BH + idx] = cn;
                }
            }
            // 8) preissue hs0F[s+1] (f0 pre-satisfied in steady state)
            if (s < TT) {
                if (w == 0) POLL128(f0, (unsigned)(s + 1));
                __syncthreads();
                const ushort* ah = hs0F + (size_t)(s + 1) * SLAB + fro;
                ISSUE(bufHa, ah); ISSUE(bufHb, ah + 4096);
            }
        }
    }
}

extern "C" void kernel_launch(void* const* d_in, const int* in_sizes, int n_in,
                              void* d_out, int out_size, void* d_ws, size_t ws_size,
                              hipStream_t stream) {
    const float* attn = (const float*)d_in[0];
    const float* x    = (const float*)d_in[1];
    const float* h0   = (const float*)d_in[3];
    const float* c0   = (const float*)d_in[4];
    const float* wah  = (const float*)d_in[5];
    const float* wih  = (const float*)d_in[6];
    const float* whh  = (const float*)d_in[7];
    const float* bah  = (const float*)d_in[8];
    const float* bih  = (const float*)d_in[9];
    const float* bhh  = (const float*)d_in[10];
    float* out = (float*)d_out;

    char* ws = (char*)d_ws;
    ushort*   Wt     = (ushort*)(ws);               // [2][4096][2048] bf16 : 33,554,432
                                                    //   (reused as h1 ring, slots 0..255)
    ushort*   xbfF   = (ushort*)(ws + 33554432);    // frag-major x     : 33,554,432
    ushort*   hs0F   = (ushort*)(ws + 67108864);    // [257] slots      : 33,685,504
    ushort*   h1s0   = (ushort*)(ws + 100794368);   // h1 ring slot 0   : 131,072
    float*    constg = (float*)(ws + 100925440);    // [2][64][4096]    : 2,097,152
    unsigned* flags  = (unsigned*)(ws + 103022592); // [256] u32 (f0|f1)
    // total 103,023,616 B

    hipLaunchKernelGGL(k_prep_wt, dim3(32, 64, 2), dim3(256), 0, stream, wih, whh, Wt);
    hipLaunchKernelGGL(k_cast_x, dim3(8192), dim3(256), 0, stream, x, xbfF);
    hipLaunchKernelGGL(k_const, dim3(16, 8, 2), dim3(256), 0, stream, attn, wah, bah, bih, bhh, constg);
    hipLaunchKernelGGL(k_init, dim3(64), dim3(256), 0, stream, h0, hs0F, h1s0, flags);

    void* args[] = { (void*)&xbfF, (void*)&hs0F, (void*)&h1s0, (void*)&Wt,
                     (void*)&constg, (void*)&c0, (void*)&out, (void*)&flags };
    hipLaunchCooperativeKernel((void*)k_persist, dim3(NBLK), dim3(512), args, 0, stream);
}

// Round 12
// 1571.883 us; speedup vs baseline: 1.3989x; 1.3129x over previous
//
#include <hip/hip_runtime.h>
#include <hip/hip_bf16.h>
#include <stdint.h>

// Problem constants
#define TT 256
#define BH 65536        // B*H
#define B4H 262144      // B*4H
#define OUT_HL 16777216
#define OUT_CL (16777216 + 131072)
#define NBLK 256
#define SLAB 65536      // ushorts per [64][1024] bf16 activation slab

typedef __attribute__((ext_vector_type(8))) short bf16x8;
typedef __attribute__((ext_vector_type(4))) float f32x4;
typedef __attribute__((ext_vector_type(4))) unsigned int u32x4;
typedef __attribute__((ext_vector_type(2))) unsigned int u32x2;

__device__ __forceinline__ ushort f2bf(float v) {
    union { float f; uint32_t u; } x; x.f = v;
    uint32_t r = x.u + 0x7fff + ((x.u >> 16) & 1);
    return (ushort)(r >> 16);
}
__device__ __forceinline__ float sigf(float x) { return 1.f / (1.f + __expf(-x)); }

// Fragment-major layout for [64][1024] bf16 activation slabs:
//   off(b,k) = (b>>4)*16384 + (k>>5)*512 + ((k>>3)&3)*128 + (b&15)*8 + (k&7)
// A wave loading m-tile m, k-group ktg reads 64 lanes x 16B CONTIGUOUS 1KB.

// Build Wt[l][col'][k] bf16, col' = u*4+g for source column col=g*1024+u.
// sc stores: region is later reused as the layer-1 h ring (plain cached reads).
__global__ __launch_bounds__(256) void k_prep_wt(const float* __restrict__ wih,
                                                 const float* __restrict__ whh,
                                                 ushort* __restrict__ Wt) {
    __shared__ ushort tile[64][65];
    const int l = blockIdx.z;
    const int k0 = blockIdx.x * 64;
    const int col0 = blockIdx.y * 64;
    const int tid = threadIdx.x;
    const int cl = tid & 63, ks = tid >> 6;
    const float* src;
    int krow0;
    if (k0 < 1024) { src = wih + (size_t)l * 1024 * 4096; krow0 = k0; }
    else           { src = whh + (size_t)l * 1024 * 4096; krow0 = k0 - 1024; }
#pragma unroll
    for (int i = 0; i < 16; ++i) {
        int kl = ks + i * 4;
        tile[kl][cl] = f2bf(src[(size_t)(krow0 + kl) * 4096 + col0 + cl]);
    }
    __syncthreads();
    const int g0 = col0 >> 10, ub = col0 & 1023;
    ushort* dst = Wt + (size_t)l * 4096 * 2048;
    const int klane = tid & 63;
#pragma unroll
    for (int i = 0; i < 16; ++i) {
        int cl2 = (tid >> 6) + i * 4;
        int row = (ub + cl2) * 4 + g0;
        ushort* p = dst + (size_t)row * 2048 + k0 + klane;
        uint v = (uint)tile[klane][cl2];
        asm volatile("global_store_short %0, %1, off sc0 sc1"
                     :: "v"(p), "v"(v) : "memory");
    }
}

// x -> bf16 fragment-major xbfF[t][...]
__global__ __launch_bounds__(256) void k_cast_x(const float* __restrict__ x,
                                                ushort* __restrict__ xbfF) {
    int i = blockIdx.x * 256 + threadIdx.x;   // [256 t][64 b][128 k8]
    int k8 = i & 127, b = (i >> 7) & 63, t = i >> 13;
    const float4* xs = (const float4*)(x + (((size_t)t * 64 + b) * 1024 + k8 * 8));
    float4 a = xs[0], c = xs[1];
    uint4 pk;
    pk.x = (uint)f2bf(a.x) | ((uint)f2bf(a.y) << 16);
    pk.y = (uint)f2bf(a.z) | ((uint)f2bf(a.w) << 16);
    pk.z = (uint)f2bf(c.x) | ((uint)f2bf(c.y) << 16);
    pk.w = (uint)f2bf(c.z) | ((uint)f2bf(c.w) << 16);
    size_t off = (size_t)t * SLAB + (size_t)(b >> 4) * 16384 +
                 (size_t)(k8 >> 2) * 512 + (size_t)(k8 & 3) * 128 + (size_t)(b & 15) * 8;
    *(uint4*)(xbfF + off) = pk;
}

// const[l][b][col] = a0[b,:] @ W_ah[l][:,col] + bias_ah + bias_ih + bias_hh
__global__ __launch_bounds__(256) void k_const(const float* __restrict__ attn,
                                               const float* __restrict__ wah,
                                               const float* __restrict__ bah,
                                               const float* __restrict__ bih,
                                               const float* __restrict__ bhh,
                                               float* __restrict__ constg) {
    const int tid = threadIdx.x;
    const int col = blockIdx.x * 256 + tid;
    const int b0 = blockIdx.y * 8;
    const int l = blockIdx.z;
    const float* W = wah + (size_t)l * 512 * 4096;
    float acc[8] = {0.f, 0.f, 0.f, 0.f, 0.f, 0.f, 0.f, 0.f};
    for (int k = 0; k < 512; ++k) {
        float wv = W[(size_t)k * 4096 + col];
#pragma unroll
        for (int j = 0; j < 8; ++j) acc[j] += attn[(b0 + j) * 512 + k] * wv;
    }
    float bias = bah[l * 4096 + col] + bih[l * 4096 + col] + bhh[l * 4096 + col];
    float* cg = constg + (size_t)l * B4H;
#pragma unroll
    for (int j = 0; j < 8; ++j) cg[(size_t)(b0 + j) * 4096 + col] = acc[j] + bias;
}

// h0 -> fragment-major initial slabs; zero flags
__global__ __launch_bounds__(256) void k_init(const float* __restrict__ h0,
                                              ushort* __restrict__ hs0F,
                                              ushort* __restrict__ h1s0,
                                              unsigned* __restrict__ flags) {
    int i = blockIdx.x * 256 + threadIdx.x;   // [2 l][64 b][128 k8] = 16384
    if (i < 16384) {
        int k8 = i & 127, b = (i >> 7) & 63, l = i >> 13;
        const float* src = h0 + ((size_t)(l * 64 + b) * 1024 + k8 * 8);
        uint4 pk;
        pk.x = (uint)f2bf(src[0]) | ((uint)f2bf(src[1]) << 16);
        pk.y = (uint)f2bf(src[2]) | ((uint)f2bf(src[3]) << 16);
        pk.z = (uint)f2bf(src[4]) | ((uint)f2bf(src[5]) << 16);
        pk.w = (uint)f2bf(src[6]) | ((uint)f2bf(src[7]) << 16);
        size_t off = (size_t)(b >> 4) * 16384 + (size_t)(k8 >> 2) * 512 +
                     (size_t)(k8 & 3) * 128 + (size_t)(b & 15) * 8;
        *(uint4*)((l == 0 ? hs0F : h1s0) + off) = pk;
    }
    if (i < NBLK) flags[i] = 0u;
}

// ---- inline-asm helpers ----
#define ISSUE(BUF, BASE)                                                       \
    do { _Pragma("unroll")                                                     \
        for (int _i = 0; _i < 8; ++_i)                                         \
            asm volatile("global_load_dwordx4 %0, %1, off"                     \
                         : "=v"(BUF[_i]) : "v"((BASE) + _i * 512)); } while (0)

// Wait (N outstanding allowed), then 8 ktg x 2 nt = 16 MFMAs.
#define CHUNK(BUF, KTG0, N, A0, A1)                                            \
    do {                                                                       \
        asm volatile("s_waitcnt vmcnt(" #N ")" ::: "memory");                  \
        __builtin_amdgcn_sched_barrier(0x100);                                 \
        _Pragma("unroll")                                                      \
        for (int _i = 0; _i < 8; ++_i) {                                       \
            int _ktg = (KTG0) + _i;                                            \
            bf16x8 _b0 = *(const bf16x8*)(wlds + (size_t)_ktg * 1024 + lane * 8);       \
            bf16x8 _b1 = *(const bf16x8*)(wlds + (size_t)_ktg * 1024 + 512 + lane * 8); \
            A0 = __builtin_amdgcn_mfma_f32_16x16x32_bf16(BUF[_i], _b0, A0, 0, 0, 0);    \
            A1 = __builtin_amdgcn_mfma_f32_16x16x32_bf16(BUF[_i], _b1, A1, 0, 0, 0);    \
        }                                                                      \
    } while (0)

// 128-flag poll, single wave, 2 flags/lane.
#define POLL128(FB, TGT)                                                       \
    do {                                                                       \
        const unsigned* _fp = (FB) + lane * 2;                                 \
        while (true) {                                                         \
            u32x2 _f;                                                          \
            asm volatile("global_load_dwordx2 %0, %1, off sc0 sc1\n\t"         \
                         "s_waitcnt vmcnt(0)"                                  \
                         : "=v"(_f) : "v"(_fp) : "memory");                    \
            if (__all(_f.x >= (TGT) && _f.y >= (TGT))) break;                  \
            __builtin_amdgcn_s_sleep(1);                                       \
        }                                                                      \
    } while (0)

// Persistent 2-layer LSTM, layer-split (r9 base). Blocks 0-127 = layer0
// (8 units each), 128-255 = layer1.
// L0 iter s: x[s] MFMA from carried regs (loaded last iter, drained) -> poll
//   f0>=s -> barrier -> issue h[s] + x[s+1] -> h MFMA -> merge -> epilogue ->
//   store hs0F[s+1] -> drain (completes x[s+1]) -> signal f0=s+1.
// L1 iter s (t=s-1): w0 polls f0>=s -> mbx[0]=s; w4 polls f1>=s -> mbx[1]=s
//   (CONCURRENT, no barrier). kh0 waves spin mbx[0] then ingest hs0F[s];
//   kh1 waves spin mbx[1] then ingest ring[t-1]. merge -> epilogue -> ring[t]
//   store -> drain -> signal f1=s+1 -> out rows.
// gt races prevented by sync1 (before epilogue) + sync2 (before next iter).
// Ring aliasing over Wt: slot t first written at iter t+1, gated by f0>=1 /
// f1 chain proving all staging reads finished (same proof as r9).
__global__ __launch_bounds__(512, 2) void k_persist(
        const ushort* __restrict__ xbfF,
        ushort* __restrict__ hs0F,
        const ushort* __restrict__ h1s0,
        ushort* Wt,                       // staging source + h1 ring (aliased)
        const float* __restrict__ constg,
        const float* __restrict__ c0,
        float* __restrict__ out,
        unsigned* __restrict__ flags) {
    __shared__ ushort wlds[65536];          // [64 ktg][2 nt][64 lane][8] = 128 KiB
    __shared__ float gt[2][4][2][16][18];   // [kh][m][nt][b&15][col'] 18 KiB
    __shared__ unsigned mbx[2];             // per-slab release mailboxes

    const int tid = threadIdx.x;
    const int w = tid >> 6, lane = tid & 63;
    const int kh = w >> 2, m = w & 3;
    const int bid = blockIdx.x;
    const int layer = bid >> 7, ub = bid & 127;
    const int u0g = ub * 8;

    // ---- stage this layer's 32 gate-cols x 2048 k into LDS (sc loads) ----
    {
        bf16x8 vst[16];
#pragma unroll
        for (int i = 0; i < 16; ++i) {
            int c = i * 512 + tid;          // 0..8191 chunks of 16B
            int lp = c & 63, nt = (c >> 6) & 1, ktg = c >> 7;
            int colp = u0g * 4 + nt * 16 + (lp & 15);
            int kk = ktg * 32 + (lp >> 4) * 8;
            const ushort* src = Wt + ((size_t)(layer * 4096 + colp)) * 2048 + kk;
            asm volatile("global_load_dwordx4 %0, %1, off sc0 sc1"
                         : "=v"(vst[i]) : "v"(src));
        }
        asm volatile("s_waitcnt vmcnt(0)" ::: "memory");
        __builtin_amdgcn_sched_barrier(0);
#pragma unroll
        for (int i = 0; i < 16; ++i) {
            int c = i * 512 + tid;
            *(bf16x8*)(wlds + (size_t)c * 8) = vst[i];
        }
    }
    if (tid == 0) { mbx[0] = 0u; mbx[1] = 0u; }

    // ---- per-thread epilogue cell: b_e = w*8 + lane/8, u_e = u0g + lane%8 ----
    const int b_e = (w << 3) | (lane >> 3);
    const int u_off = lane & 7;
    const int u_e = u0g + u_off;
    float cg[4];
#pragma unroll
    for (int g = 0; g < 4; ++g)
        cg[g] = constg[(size_t)layer * B4H + (size_t)b_e * 4096 + g * 1024 + u_e];
    float creg = c0[layer * BH + b_e * 1024 + u_e];
    const int mb = b_e >> 4, blb = b_e & 15, ntb = u_off >> 2, cpb = (u_off & 3) * 4;
    const size_t hoffL = (size_t)mb * 16384 + (size_t)(ub >> 2) * 512 +
                         (size_t)(ub & 3) * 128 + (size_t)blb * 8;

    const size_t fro = (size_t)m * 16384 + (size_t)lane * 8;
    unsigned* f0 = flags;
    unsigned* f1 = flags + 128;

    __syncthreads();

    if (layer == 0) {
        bf16x8 bufXa[8], bufXb[8];
        // prologue: load x[0], complete (landed regs are safe to carry)
        {
            const ushort* ax = xbfF + fro + kh * 8192;
            ISSUE(bufXa, ax); ISSUE(bufXb, ax + 4096);
            asm volatile("s_waitcnt vmcnt(0)" ::: "memory");
            __builtin_amdgcn_sched_barrier(0);
        }
        for (int s = 0; s < TT; ++s) {
            f32x4 aE0 = {0,0,0,0}, aO0 = {0,0,0,0};
            f32x4 aE1 = {0,0,0,0}, aO1 = {0,0,0,0};
            bf16x8 bufHa[8], bufHb[8];
            // 1) x[s] MFMA from resident carried regs (vmcnt 0 outstanding)
            CHUNK(bufXa, kh * 16,     0, aE0, aE1);
            CHUNK(bufXb, kh * 16 + 8, 0, aO0, aO1);
            // 2) poll own-layer peers (their iter s-1) + release
            if (s >= 1 && w == 0) POLL128(f0, (unsigned)s);
            __syncthreads();
            // 3) h[s] ingest + x[s+1] issue + h MFMA
            {
                const ushort* ah = hs0F + (size_t)s * SLAB + fro + kh * 8192;
                ISSUE(bufHa, ah); ISSUE(bufHb, ah + 4096);          // 16 out
                const ushort* ax = xbfF + (size_t)((s + 1) & 255) * SLAB + fro + kh * 8192;
                ISSUE(bufXa, ax); ISSUE(bufXb, ax + 4096);          // 32 out
                CHUNK(bufHa, 32 + kh * 16,     24, aE0, aE1);       // first 8 h
                CHUNK(bufHb, 32 + kh * 16 + 8, 16, aO0, aO1);       // rest of h
            }
            // 4) merge partials
            {
                const int cc = lane & 15, r0 = (lane >> 4) * 4;
#pragma unroll
                for (int r = 0; r < 4; ++r) {
                    gt[kh][m][0][r0 + r][cc] = aE0[r] + aO0[r];
                    gt[kh][m][1][r0 + r][cc] = aE1[r] + aO1[r];
                }
            }
            __syncthreads();                              // sync1
            // 5) balanced cell epilogue
            float g4[4];
#pragma unroll
            for (int g = 0; g < 4; ++g)
                g4[g] = gt[0][mb][ntb][blb][cpb + g] + gt[1][mb][ntb][blb][cpb + g] + cg[g];
            float si = sigf(g4[0]), sf = sigf(g4[1]), so = sigf(g4[3]);
            float cn = sf * creg + si * (2.f * sigf(2.f * g4[2]) - 1.f);
            float hv = so * (2.f * sigf(2.f * cn) - 1.f);
            creg = cn;
            uint hb = (uint)f2bf(hv);
            uint p0 = __shfl(hb, (lane & 56) + 0), p1 = __shfl(hb, (lane & 56) + 1);
            uint p2 = __shfl(hb, (lane & 56) + 2), p3 = __shfl(hb, (lane & 56) + 3);
            uint p4 = __shfl(hb, (lane & 56) + 4), p5 = __shfl(hb, (lane & 56) + 5);
            uint p6 = __shfl(hb, (lane & 56) + 6), p7 = __shfl(hb, (lane & 56) + 7);
            u32x4 hp;
            hp.x = (p0 & 0xffffu) | (p1 << 16);
            hp.y = (p2 & 0xffffu) | (p3 << 16);
            hp.z = (p4 & 0xffffu) | (p5 << 16);
            hp.w = (p6 & 0xffffu) | (p7 << 16);
            ushort* hdst = hs0F + (size_t)(s + 1) * SLAB + hoffL;
            if (u_off == 0)
                asm volatile("global_store_dwordx4 %0, %1, off sc0 sc1"
                             :: "v"(hdst), "v"(hp) : "memory");
            // 6) drain (h-store + x[s+1] loads), sync, signal
            asm volatile("s_waitcnt vmcnt(0)" ::: "memory");
            __syncthreads();                              // sync2
            if (tid == 0) {
                unsigned tgt = (unsigned)(s + 1);
                unsigned* fp = f0 + ub;
                asm volatile("global_store_dword %0, %1, off sc0 sc1"
                             :: "v"(fp), "v"(tgt) : "memory");
            }
            // 7) exit-only stores
            if (s == TT - 1) {
                int idx = b_e * 1024 + u_e;
                out[OUT_HL + idx] = hv;
                out[OUT_CL + idx] = cn;
            }
        }
    } else {
        for (int s = 1; s <= TT; ++s) {
            const int t1 = s - 1;
            f32x4 aE0 = {0,0,0,0}, aO0 = {0,0,0,0};
            f32x4 aE1 = {0,0,0,0}, aO1 = {0,0,0,0};
            bf16x8 bufA[8], bufB[8], bufC[8], bufD[8];
            // 1) concurrent pollers -> mailboxes (no barrier)
            if (w == 0) {
                POLL128(f0, (unsigned)s);
                if (lane == 0)
                    __hip_atomic_store(&mbx[0], (unsigned)s, __ATOMIC_RELEASE,
                                       __HIP_MEMORY_SCOPE_WORKGROUP);
            }
            if (w == 4) {
                if (s >= 2) POLL128(f1, (unsigned)s);
                if (lane == 0)
                    __hip_atomic_store(&mbx[1], (unsigned)s, __ATOMIC_RELEASE,
                                       __HIP_MEMORY_SCOPE_WORKGROUP);
            }
            // 2) spin own-slab mailbox (LDS; kh0 released by f0, kh1 by f1)
            while (__hip_atomic_load(&mbx[kh], __ATOMIC_ACQUIRE,
                                     __HIP_MEMORY_SCOPE_WORKGROUP) < (unsigned)s)
                __builtin_amdgcn_s_sleep(1);
            // 3) ingest own slab + MFMA (kh0: hs0F[s]; kh1: ring[t1-1])
            {
                const ushort* a = (kh == 0)
                    ? hs0F + (size_t)s * SLAB + fro
                    : (t1 == 0 ? h1s0 + fro
                               : (const ushort*)Wt + (size_t)(t1 - 1) * SLAB + fro);
                ISSUE(bufA, a);
                ISSUE(bufB, a + 4096);
                ISSUE(bufC, a + 8192);
                ISSUE(bufD, a + 12288);
                CHUNK(bufA, kh * 32,      24, aE0, aE1);
                CHUNK(bufB, kh * 32 + 8,  16, aO0, aO1);
                CHUNK(bufC, kh * 32 + 16,  8, aE0, aE1);
                CHUNK(bufD, kh * 32 + 24,  0, aO0, aO1);
            }
            // 4) merge partials
            {
                const int cc = lane & 15, r0 = (lane >> 4) * 4;
#pragma unroll
                for (int r = 0; r < 4; ++r) {
                    gt[kh][m][0][r0 + r][cc] = aE0[r] + aO0[r];
                    gt[kh][m][1][r0 + r][cc] = aE1[r] + aO1[r];
                }
            }
            __syncthreads();                              // sync1
            // 5) balanced cell epilogue
            float g4[4];
#pragma unroll
            for (int g = 0; g < 4; ++g)
                g4[g] = gt[0][mb][ntb][blb][cpb + g] + gt[1][mb][ntb][blb][cpb + g] + cg[g];
            float si = sigf(g4[0]), sf = sigf(g4[1]), so = sigf(g4[3]);
            float cn = sf * creg + si * (2.f * sigf(2.f * g4[2]) - 1.f);
            float hv = so * (2.f * sigf(2.f * cn) - 1.f);
            creg = cn;
            uint hb = (uint)f2bf(hv);
            uint p0 = __shfl(hb, (lane & 56) + 0), p1 = __shfl(hb, (lane & 56) + 1);
            uint p2 = __shfl(hb, (lane & 56) + 2), p3 = __shfl(hb, (lane & 56) + 3);
            uint p4 = __shfl(hb, (lane & 56) + 4), p5 = __shfl(hb, (lane & 56) + 5);
            uint p6 = __shfl(hb, (lane & 56) + 6), p7 = __shfl(hb, (lane & 56) + 7);
            u32x4 hp;
            hp.x = (p0 & 0xffffu) | (p1 << 16);
            hp.y = (p2 & 0xffffu) | (p3 << 16);
            hp.z = (p4 & 0xffffu) | (p5 << 16);
            hp.w = (p6 & 0xffffu) | (p7 << 16);
            ushort* hdst = Wt + (size_t)t1 * SLAB + hoffL;   // ring slot t1
            if (u_off == 0)
                asm volatile("global_store_dwordx4 %0, %1, off sc0 sc1"
                             :: "v"(hdst), "v"(hp) : "memory");
            // 6) drain + sync + signal
            asm volatile("s_waitcnt vmcnt(0)" ::: "memory");
            __syncthreads();                              // sync2
            if (tid == 0) {
                unsigned tgt = (unsigned)(s + 1);
                unsigned* fp = f1 + ub;
                asm volatile("global_store_dword %0, %1, off sc0 sc1"
                             :: "v"(fp), "v"(tgt) : "memory");
            }
            // 7) output rows (exit-only data; overlaps next iteration)
            {
                float o0 = __shfl(hv, (lane & 56) + 0), o1 = __shfl(hv, (lane & 56) + 1);
                float o2 = __shfl(hv, (lane & 56) + 2), o3 = __shfl(hv, (lane & 56) + 3);
                float o4 = __shfl(hv, (lane & 56) + 4), o5 = __shfl(hv, (lane & 56) + 5);
                float o6 = __shfl(hv, (lane & 56) + 6), o7 = __shfl(hv, (lane & 56) + 7);
                if (u_off == 0) {
                    float* op = out + (size_t)t1 * BH + (size_t)b_e * 1024 + u0g;
                    float4 v0 = {o0, o1, o2, o3}, v1 = {o4, o5, o6, o7};
                    *(float4*)op = v0;
                    *(float4*)(op + 4) = v1;
                }
                if (t1 == TT - 1) {
                    int idx = b_e * 1024 + u_e;
                    out[OUT_HL + BH + idx] = hv;
                    out[OUT_CL + BH + idx] = cn;
                }
            }
        }
    }
}

extern "C" void kernel_launch(void* const* d_in, const int* in_sizes, int n_in,
                              void* d_out, int out_size, void* d_ws, size_t ws_size,
                              hipStream_t stream) {
    const float* attn = (const float*)d_in[0];
    const float* x    = (const float*)d_in[1];
    const float* h0   = (const float*)d_in[3];
    const float* c0   = (const float*)d_in[4];
    const float* wah  = (const float*)d_in[5];
    const float* wih  = (const float*)d_in[6];
    const float* whh  = (const float*)d_in[7];
    const float* bah  = (const float*)d_in[8];
    const float* bih  = (const float*)d_in[9];
    const float* bhh  = (const float*)d_in[10];
    float* out = (float*)d_out;

    char* ws = (char*)d_ws;
    ushort*   Wt     = (ushort*)(ws);               // [2][4096][2048] bf16 : 33,554,432
                                                    //   (reused as h1 ring, slots 0..255)
    ushort*   xbfF   = (ushort*)(ws + 33554432);    // frag-major x     : 33,554,432
    ushort*   hs0F   = (ushort*)(ws + 67108864);    // [257] slots      : 33,685,504
    ushort*   h1s0   = (ushort*)(ws + 100794368);   // h1 ring slot 0   : 131,072
    float*    constg = (float*)(ws + 100925440);    // [2][64][4096]    : 2,097,152
    unsigned* flags  = (unsigned*)(ws + 103022592); // [256] u32 (f0|f1)
    // total 103,023,616 B

    hipLaunchKernelGGL(k_prep_wt, dim3(32, 64, 2), dim3(256), 0, stream, wih, whh, Wt);
    hipLaunchKernelGGL(k_cast_x, dim3(8192), dim3(256), 0, stream, x, xbfF);
    hipLaunchKernelGGL(k_const, dim3(16, 8, 2), dim3(256), 0, stream, attn, wah, bah, bih, bhh, constg);
    hipLaunchKernelGGL(k_init, dim3(64), dim3(256), 0, stream, h0, hs0F, h1s0, flags);

    void* args[] = { (void*)&xbfF, (void*)&hs0F, (void*)&h1s0, (void*)&Wt,
                     (void*)&constg, (void*)&c0, (void*)&out, (void*)&flags };
    hipLaunchCooperativeKernel((void*)k_persist, dim3(NBLK), dim3(512), args, 0, stream);
}